// Round 8
// baseline (160.443 us; speedup 1.0000x reference)
//
#include <hip/hip_runtime.h>
#include <math.h>

// YOLO box decode: (32, 3*85, 52, 52) -> (32*3*52*52, 85)
// Persistent waves, per-wave private 16x85 LDS transpose tile. ALL FOUR
// tiles' loads prefetched up front (24 global_load_dwordx4 = ~24KB in
// flight per wave), consumed tile-by-tile -> compiler emits fine-grained
// vmcnt(18/12/6/0) waits; loads stay in flight across every LDS/store phase.
// R7 bug fixed: DEPTH=3 with TPW=4 aliased v[0] (prefetch for tile 3 wrote
// the buffer tile 0 was about to consume). DEPTH==TPW removes rotation.
// Correctness: s_waitcnt lgkmcnt(0) + memory clobber between LDS scatter
// writes and b128 read-back (intra-wave LDS RAW; raced in R3 without it).

typedef float nat_float4 __attribute__((ext_vector_type(4)));

#define NSPAT   2704          // 52*52
#define NCH     85            // 5 + 80 classes
#define WTILE_S 16            // spatial positions per wave-tile
#define WITEMS  340           // float4 items per tile = 16*85/4
#define NSLOTS  6             // ceil(340/64)
#define WPB     4             // waves per block (256 threads)
#define TILES_PER_SLAB 169    // 2704/16
#define NBLOCKS 1014          // 4056 waves total
#define NWAVES  (NBLOCKS * WPB)   // 4056 -> exactly 4 tiles per wave
#define TPW     4             // tiles per wave == prefetch depth

__global__ __launch_bounds__(256) void yolo_decode_kernel(
    const float* __restrict__ in, float* __restrict__ out) {
  __shared__ __align__(16) float tile[WPB][WTILE_S * NCH];  // 21760 B/block

  const int lane = threadIdx.x & 63;
  const int widx = threadIdx.x >> 6;
  float* slice = tile[widx];
  const int gw0 = blockIdx.x * WPB + widx;   // first tile of this wave

  // per-lane item decomposition (constant across tiles)
  const int lc[NSLOTS] = { (lane + 0) >> 2, (lane + 64) >> 2, (lane + 128) >> 2,
                           (lane + 192) >> 2, (lane + 256) >> 2, (lane + 320) >> 2 };
  const int lq = lane & 3;   // q == lane&3 for every slot (64 % 4 == 0)

  nat_float4 v[TPW][NSLOTS];   // 96 data VGPRs: all four tiles in flight

  // ---- prefetch ALL tiles 0..3 (24 loads outstanding) ----
  #pragma unroll
  for (int p = 0; p < TPW; ++p) {
    const int t    = gw0 + p * NWAVES;
    const int slab = t / TILES_PER_SLAB;
    const int tt   = t - slab * TILES_PER_SLAB;
    const float* src = in + (long)slab * (NCH * NSPAT) + tt * WTILE_S + 4 * lq;
    #pragma unroll
    for (int k = 0; k < NSLOTS; ++k) {
      if (lane + 64 * k < WITEMS)
        v[p][k] = *(const nat_float4*)(src + lc[k] * NSPAT);
    }
  }

  #pragma unroll
  for (int i = 0; i < TPW; ++i) {
    // ---- transform tile i + stage to private LDS slice (output layout) ----
    const int t    = gw0 + i * NWAVES;
    const int slab = t / TILES_PER_SLAB;
    const int tt   = t - slab * TILES_PER_SLAB;
    const int a    = slab % 3;                       // ANCHOR_MASK = [0,1,2]
    const float aw = (a == 0) ? 10.0f : (a == 1) ? 16.0f : 33.0f;
    const float ah = (a == 0) ? 13.0f : (a == 1) ? 30.0f : 23.0f;
    const long base = (long)slab * (NCH * NSPAT);
    const int s0   = tt * WTILE_S;

    #pragma unroll
    for (int k = 0; k < NSLOTS; ++k) {
      const int idx = lane + 64 * k;
      if (idx < WITEMS) {
        const int c = lc[k];
        nat_float4 val = v[i][k];
        float e[4] = {val.x, val.y, val.z, val.w};
        if (c < 5) {               // only lanes 0..19 of slot 0 diverge
          #pragma unroll
          for (int j = 0; j < 4; ++j) {
            const int sg = s0 + 4 * lq + j;  // global spatial index: h*52 + w
            float x = e[j];
            if (c == 0)      x = 1.0f / (1.0f + __expf(-x)) + (float)(sg % 52);
            else if (c == 1) x = 1.0f / (1.0f + __expf(-x)) + (float)(sg / 52);
            else if (c == 2) x = __expf(x * (1.0f / 416.0f)) * aw;
            else if (c == 3) x = __expf(x * (1.0f / 416.0f)) * ah;
            else             x = 1.0f / (1.0f + __expf(-x));
            e[j] = x;
          }
        }
        #pragma unroll
        for (int j = 0; j < 4; ++j)
          slice[(4 * lq + j) * NCH + c] = e[j];  // ~2-3-way bank aliasing: free
      }
    }

    // intra-wave LDS RAW: all ds_writes must complete before b128 read-back
    asm volatile("s_waitcnt lgkmcnt(0)" ::: "memory");

    // ---- contiguous NT float4 write-out of this tile's 1360 floats ----
    const nat_float4* s4 = (const nat_float4*)slice;
    nat_float4* dst = (nat_float4*)(out + base + s0 * NCH);  // 16B-aligned
    #pragma unroll
    for (int k = 0; k < NSLOTS; ++k) {
      const int idx = lane + 64 * k;
      if (idx < WITEMS) __builtin_nontemporal_store(s4[idx], dst + idx);
    }

    // pin ds_read(i) before ds_write(i+1) at compile time
    asm volatile("" ::: "memory");
  }
}

extern "C" void kernel_launch(void* const* d_in, const int* in_sizes, int n_in,
                              void* d_out, int out_size, void* d_ws, size_t ws_size,
                              hipStream_t stream) {
  const float* in = (const float*)d_in[0];
  float* out = (float*)d_out;
  yolo_decode_kernel<<<NBLOCKS, 256, 0, stream>>>(in, out);
}

// Round 9
// 155.949 us; speedup vs baseline: 1.0288x; 1.0288x over previous
//
#include <hip/hip_runtime.h>
#include <math.h>

// YOLO box decode: (32, 3*85, 52, 52) -> (32*3*52*52, 85)
// R9: COPY-LIKE READ INSTRUCTIONS. R2/R5/R6/R8 all plateau at ~2.6 TB/s
// independent of run length, barriers, occupancy, software MLP, NT ->
// per-CU miss-handling saturates at ~4.3 B/cyc with 64B-granule scattered
// instruction footprints. Copy kernels (6.3 TB/s) differ in ONE remaining
// way: each wave-instruction covers one large CONTIGUOUS span, allowing
// the pipe to merge lines per miss-slot. Here every global load instruction
// is a single contiguous 416 B run: wave w owns 17 channels (85=5*17), one
// dwordx2 load per channel (52 lanes x 8B sweep s). Block = 5 waves owns
// [85ch x 104sp], LDS [s][c] transpose tile (35.4 KB -> 4 blocks/CU), then
// one fully contiguous 35.4 KB NT float4 store run per block.

typedef float nat_float4 __attribute__((ext_vector_type(4)));
typedef float nat_float2 __attribute__((ext_vector_type(2)));

#define NSPAT   2704          // 52*52
#define NCH     85            // 5 + 80 classes
#define STILE   104           // spatial positions per block (2704 = 26*104)
#define NTILES  26
#define NSLAB   96            // 32 batches * 3 anchors
#define WPB     5             // waves per block (320 threads)
#define CPW     17            // channels per wave (85 = 5*17)
#define NITEMS  2210          // float4s per tile = 104*85/4

__global__ __launch_bounds__(320) void yolo_decode_kernel(
    const float* __restrict__ in, float* __restrict__ out) {
  __shared__ __align__(16) float tile[STILE * NCH];  // 35360 B, [s][c]

  const int lane = threadIdx.x & 63;
  const int w    = threadIdx.x >> 6;         // 0..4
  const int slab = blockIdx.x / NTILES;      // b*3 + a
  const int tt   = blockIdx.x - slab * NTILES;
  const int a    = slab % 3;                 // ANCHOR_MASK = [0,1,2]

  const float aw = (a == 0) ? 10.0f : (a == 1) ? 16.0f : 33.0f;
  const float ah = (a == 0) ? 13.0f : (a == 1) ? 30.0f : 23.0f;

  const long base = (long)slab * (NCH * NSPAT);
  const int  s0   = tt * STILE;
  const int  c0   = w * CPW;

  // ---- Phase 1: 17 loads, EACH one contiguous 416 B run (52 lanes x 8 B) ----
  nat_float2 v[CPW];
  const bool active = (lane < 52);
  const float* src = in + base + (long)c0 * NSPAT + s0 + 2 * lane;
  #pragma unroll
  for (int j = 0; j < CPW; ++j) {
    if (active) v[j] = *(const nat_float2*)(src + j * NSPAT);
  }

  // ---- Phase 2: transform + stage to LDS in output layout [s][c] ----
  if (active) {
    const int sl = 2 * lane;                 // local spatial 0..103 (even)
    #pragma unroll
    for (int j = 0; j < CPW; ++j) {
      const int c = c0 + j;
      float e[2] = {v[j].x, v[j].y};
      if (c < 5) {                           // only wave 0, channels 0..4
        #pragma unroll
        for (int j2 = 0; j2 < 2; ++j2) {
          const int sg = s0 + sl + j2;       // global spatial: h*52 + w
          float x = e[j2];
          if (c == 0)      x = 1.0f / (1.0f + __expf(-x)) + (float)(sg % 52);
          else if (c == 1) x = 1.0f / (1.0f + __expf(-x)) + (float)(sg / 52);
          else if (c == 2) x = __expf(x * (1.0f / 416.0f)) * aw;
          else if (c == 3) x = __expf(x * (1.0f / 416.0f)) * ah;
          else             x = 1.0f / (1.0f + __expf(-x));
          e[j2] = x;
        }
      }
      tile[sl * NCH + c]       = e[0];       // lane stride 170 dw -> ~3-way
      tile[(sl + 1) * NCH + c] = e[1];       //   bank aliasing: near-free
    }
  }

  __syncthreads();

  // ---- Phase 3: one fully contiguous 35,360 B NT store run per block ----
  const nat_float4* s4 = (const nat_float4*)tile;
  nat_float4* dst = (nat_float4*)(out + base + (long)s0 * NCH);
  for (int idx = threadIdx.x; idx < NITEMS; idx += 320) {
    __builtin_nontemporal_store(s4[idx], dst + idx);  // LDS reads stride-1
  }
}

extern "C" void kernel_launch(void* const* d_in, const int* in_sizes, int n_in,
                              void* d_out, int out_size, void* d_ws, size_t ws_size,
                              hipStream_t stream) {
  const float* in = (const float*)d_in[0];
  float* out = (float*)d_out;
  yolo_decode_kernel<<<NSLAB * NTILES, 320, 0, stream>>>(in, out);
}